// Round 1
// baseline (12020.199 us; speedup 1.0000x reference)
//
#include <hip/hip_runtime.h>

// Problem constants
constexpr int Bn = 8, Tn = 16, Nn = 512, Cn = 64, Hn = 64, En = 16384, Ln = 2;
constexpr int NC = Nn * Cn;           // 32768, slice stride for (b,t) or (b) slices
constexpr int MROWS = Bn * Nn;        // 4096

// ---------------- workspace layout (in floats) ----------------
constexpr size_t OFF_DEG   = 0;                          // 512
constexpr size_t OFF_DINV  = 512;                        // 512
constexpr size_t OFF_NW    = 1024;                       // E
constexpr size_t OFF_CSRW  = OFF_NW + En;                // E
constexpr size_t OFF_INT   = OFF_CSRW + En;              // int area below (in ints)
//   ints: counts[512] @0, cursor[512] @512, csr_off[513->576] @1024, csr_src[E] @1664
constexpr size_t INT_COUNTS = 0, INT_CURSOR = 512, INT_CSROFF = 1024, INT_CSRSRC = 1664;
constexpr size_t INT_TOTAL  = 1664 + En;                 // 18048 ints
constexpr size_t OFF_WZR = OFF_INT + INT_TOTAL;          // 2*384*128 = 98304
constexpr size_t OFF_WHT = OFF_WZR + 2*384*128;          // 2*384*64 = 49152
constexpr size_t OFF_BZR = OFF_WHT + 2*384*64;           // 256
constexpr size_t OFF_BHT = OFF_BZR + 256;                // 128
constexpr size_t OFF_W1C = OFF_BHT + 128;                // 8192
constexpr size_t OFF_T1X = OFF_W1C + 8192;               // B*T*N*C = 4194304
constexpr size_t OFF_T2X = OFF_T1X + (size_t)Bn*Tn*NC;
constexpr size_t OFF_H   = OFF_T2X + (size_t)Bn*Tn*NC;   // B*N*H = 262144
constexpr size_t OFF_U1  = OFF_H   + (size_t)Bn*NC;
constexpr size_t OFF_U2  = OFF_U1  + (size_t)Bn*NC;
constexpr size_t OFF_Z   = OFF_U2  + (size_t)Bn*NC;
constexpr size_t OFF_HR  = OFF_Z   + (size_t)Bn*NC;
constexpr size_t OFF_V1  = OFF_HR  + (size_t)Bn*NC;
constexpr size_t OFF_V2  = OFF_V1  + (size_t)Bn*NC;
constexpr size_t OFF_SP  = OFF_V2  + (size_t)Bn*NC;      // 4096*64
constexpr size_t OFF_TP  = OFF_SP  + (size_t)MROWS*Hn;
constexpr size_t OFF_END = OFF_TP  + (size_t)MROWS*Hn;   // ~11.0M floats ~44MB

// ---------------- setup kernels ----------------
__global__ void k_deg(const float* __restrict__ w, const int* __restrict__ src,
                      float* __restrict__ deg) {
    int e = blockIdx.x * 256 + threadIdx.x;
    if (e < En) atomicAdd(&deg[src[e]], w[e]);
}

__global__ void k_dinv(const float* __restrict__ deg, float* __restrict__ dinv) {
    int n = blockIdx.x * 256 + threadIdx.x;
    if (n < Nn) {
        float d = deg[n];
        dinv[n] = d > 0.f ? rsqrtf(fmaxf(d, 1e-12f)) : 0.f;
    }
}

__global__ void k_normw(const float* __restrict__ w, const int* __restrict__ src,
                        const int* __restrict__ dst, const float* __restrict__ dinv,
                        float* __restrict__ nw, int* __restrict__ counts) {
    int e = blockIdx.x * 256 + threadIdx.x;
    if (e < En) {
        nw[e] = -w[e] * dinv[src[e]] * dinv[dst[e]];
        atomicAdd(&counts[dst[e]], 1);
    }
}

__global__ void k_scan(const int* __restrict__ counts, int* __restrict__ csr_off,
                       int* __restrict__ cursor) {
    __shared__ int s[512];
    int tid = threadIdx.x;   // 512 threads
    int c = counts[tid];
    s[tid] = c;
    __syncthreads();
    for (int d = 1; d < 512; d <<= 1) {
        int v = (tid >= d) ? s[tid - d] : 0;
        __syncthreads();
        s[tid] += v;
        __syncthreads();
    }
    csr_off[tid + 1] = s[tid];
    if (tid == 0) csr_off[0] = 0;
    cursor[tid] = s[tid] - c;   // exclusive
}

__global__ void k_fill(const int* __restrict__ src, const int* __restrict__ dst,
                       const float* __restrict__ nw, int* __restrict__ cursor,
                       int* __restrict__ csr_src, float* __restrict__ csr_w) {
    int e = blockIdx.x * 256 + threadIdx.x;
    if (e < En) {
        int p = atomicAdd(&cursor[dst[e]], 1);
        csr_src[p] = src[e];
        csr_w[p] = nw[e];
    }
}

// repack weights: WzrC[l][384][128], WhC[l][384][64], bzr[l][128], bht[l][64], W1cat[64][128]
__global__ void k_repack(const float* __restrict__ Wx, const float* __restrict__ bx,
                         const float* __restrict__ Wh, const float* __restrict__ bh,
                         const float* __restrict__ W1,
                         float* __restrict__ WzrC, float* __restrict__ WhC,
                         float* __restrict__ bzr, float* __restrict__ bht,
                         float* __restrict__ W1cat) {
    int idx = blockIdx.x * 256 + threadIdx.x;
    if (idx < 98304) {
        int l = idx / 49152, r = idx % 49152;
        int k = r / 128, j = r % 128;
        int g = j >> 6, hh = j & 63;
        int kc, c; const float* s;
        if (k < 192) { kc = k / 64; c = k % 64; s = Wh; }
        else { kc = (k - 192) / 64; c = (k - 192) % 64; s = Wx; }
        WzrC[idx] = s[((((size_t)(l*3 + g))*3 + kc)*64 + c)*64 + hh];
    } else if (idx < 147456) {
        int tI = idx - 98304;
        int l = tI / 24576, r = tI % 24576;
        int k = r / 64, hh = r % 64;
        int kc, c; const float* s;
        if (k < 192) { kc = k / 64; c = k % 64; s = Wh; }
        else { kc = (k - 192) / 64; c = (k - 192) % 64; s = Wx; }
        WhC[tI] = s[((((size_t)(l*3 + 2))*3 + kc)*64 + c)*64 + hh];
    } else if (idx < 147712) {
        int tI = idx - 147456;
        int l = tI >> 7, j = tI & 127;
        int g = j >> 6, hh = j & 63;
        bzr[tI] = bh[(l*3 + g)*64 + hh] + bx[(l*3 + g)*64 + hh];
    } else if (idx < 147840) {
        int tI = idx - 147712;
        int l = tI >> 6, hh = tI & 63;
        bht[tI] = bh[(l*3 + 2)*64 + hh] + bx[(l*3 + 2)*64 + hh];
    } else if (idx < 156032) {
        int tI = idx - 147840;
        int c = tI >> 7, j = tI & 127;
        W1cat[tI] = (j < 64) ? W1[c*64 + j] : W1[(64 + c)*64 + (j - 64)];
    }
}

// ---------------- CSR gather: out[s][n][c] = alpha*sum_j w_j*u[s][src_j][c] + beta*base[s][n][c]
// grid = slices*16, block=256; 32 nodes per block, C=64
__global__ __launch_bounds__(256) void k_gather(
        const float* __restrict__ u, const float* __restrict__ base,
        float* __restrict__ out,
        const int* __restrict__ csr_off, const int* __restrict__ csr_src,
        const float* __restrict__ csr_w, float alpha, float beta) {
    int chunk = blockIdx.x & 15;
    int slice = blockIdx.x >> 4;
    const float* us = u + (size_t)slice * NC;
    float* os = out + (size_t)slice * NC;
    const float* bs = base + (size_t)slice * NC;   // only read if beta != 0
    int c = threadIdx.x & 63, nl = threadIdx.x >> 6;
    for (int i = 0; i < 8; i++) {
        int n = chunk * 32 + i * 4 + nl;
        int e0 = csr_off[n], e1 = csr_off[n + 1];
        float acc = 0.f;
        for (int j = e0; j < e1; j++) {
            acc += csr_w[j] * us[csr_src[j] * 64 + c];
        }
        float r = alpha * acc;
        if (beta != 0.f) r += beta * bs[n * 64 + c];
        os[n * 64 + c] = r;
    }
}

// ---------------- z,r kernel: rows=4096, cols=128, K=384 over 6 segments ----------------
// grid = 128 (32 rows/block), block = 256
__global__ __launch_bounds__(256) void k_zr(
        const float* __restrict__ h, const float* __restrict__ u1, const float* __restrict__ u2,
        const float* __restrict__ x, const float* __restrict__ t1x, const float* __restrict__ t2x,
        const float* __restrict__ W, const float* __restrict__ bias,
        float* __restrict__ z, float* __restrict__ hr, int t) {
    __shared__ float As[16][33];
    __shared__ float Ws[16 * 128];
    int tid = threadIdx.x;
    int row0 = blockIdx.x * 32;
    int b = row0 >> 9;
    size_t hoff = (size_t)row0 * 64;
    size_t xoff = ((size_t)(b * Tn + t) * Nn + (row0 & 511)) * 64;
    const float* seg[6] = { h + hoff, u1 + hoff, u2 + hoff, x + xoff, t1x + xoff, t2x + xoff };
    float acc[2][8];
#pragma unroll
    for (int i = 0; i < 2; i++)
#pragma unroll
        for (int j = 0; j < 8; j++) acc[i][j] = 0.f;
    int tx = tid & 15, ty = tid >> 4;
    int lr = tid >> 3;           // A-load row 0..31
    int lk = (tid & 7) * 2;      // A-load k pair
    int wk = tid >> 4;           // W-load k 0..15
    int wc = (tid & 15) * 8;     // W-load col
    for (int kt = 0; kt < 24; kt++) {
        const float* sp = seg[kt >> 2];
        int c0 = (kt & 3) * 16;
        float2 a2 = *(const float2*)&sp[lr * 64 + c0 + lk];
        const float4* wsrc = (const float4*)&W[(size_t)(kt * 16 + wk) * 128 + wc];
        float4 w0 = wsrc[0], w1 = wsrc[1];
        As[lk][lr] = a2.x;
        As[lk + 1][lr] = a2.y;
        *(float4*)&Ws[wk * 128 + wc] = w0;
        *(float4*)&Ws[wk * 128 + wc + 4] = w1;
        __syncthreads();
#pragma unroll
        for (int kk = 0; kk < 16; kk++) {
            float a0 = As[kk][ty * 2 + 0];
            float a1 = As[kk][ty * 2 + 1];
            float4 p0 = *(const float4*)&Ws[kk * 128 + tx * 8];
            float4 p1 = *(const float4*)&Ws[kk * 128 + tx * 8 + 4];
            float w[8] = { p0.x, p0.y, p0.z, p0.w, p1.x, p1.y, p1.z, p1.w };
#pragma unroll
            for (int cc = 0; cc < 8; cc++) {
                acc[0][cc] += a0 * w[cc];
                acc[1][cc] += a1 * w[cc];
            }
        }
        __syncthreads();
    }
#pragma unroll
    for (int rr = 0; rr < 2; rr++) {
        int row = row0 + ty * 2 + rr;
#pragma unroll
        for (int cc = 0; cc < 8; cc++) {
            int col = tx * 8 + cc;
            float v = acc[rr][cc] + bias[col];
            float s = 1.f / (1.f + __expf(-v));
            if (col < 64) {
                z[(size_t)row * 64 + col] = s;
            } else {
                size_t p = (size_t)row * 64 + (col - 64);
                hr[p] = h[p] * s;
            }
        }
    }
}

// ---------------- h_tilde + GRU update: rows=4096, cols=64, K=384 ----------------
__global__ __launch_bounds__(256) void k_ht(
        const float* __restrict__ hr, const float* __restrict__ v1, const float* __restrict__ v2,
        const float* __restrict__ x, const float* __restrict__ t1x, const float* __restrict__ t2x,
        const float* __restrict__ W, const float* __restrict__ bias,
        const float* __restrict__ z, float* __restrict__ h, int t) {
    __shared__ float As[16][33];
    __shared__ float Ws[16 * 64];
    int tid = threadIdx.x;
    int row0 = blockIdx.x * 32;
    int b = row0 >> 9;
    size_t hoff = (size_t)row0 * 64;
    size_t xoff = ((size_t)(b * Tn + t) * Nn + (row0 & 511)) * 64;
    const float* seg[6] = { hr + hoff, v1 + hoff, v2 + hoff, x + xoff, t1x + xoff, t2x + xoff };
    float acc[2][4];
#pragma unroll
    for (int i = 0; i < 2; i++)
#pragma unroll
        for (int j = 0; j < 4; j++) acc[i][j] = 0.f;
    int tx = tid & 15, ty = tid >> 4;
    int lr = tid >> 3;
    int lk = (tid & 7) * 2;
    int wk = tid >> 4;
    int wc = (tid & 15) * 4;
    for (int kt = 0; kt < 24; kt++) {
        const float* sp = seg[kt >> 2];
        int c0 = (kt & 3) * 16;
        float2 a2 = *(const float2*)&sp[lr * 64 + c0 + lk];
        float4 w0 = *(const float4*)&W[(size_t)(kt * 16 + wk) * 64 + wc];
        As[lk][lr] = a2.x;
        As[lk + 1][lr] = a2.y;
        *(float4*)&Ws[wk * 64 + wc] = w0;
        __syncthreads();
#pragma unroll
        for (int kk = 0; kk < 16; kk++) {
            float a0 = As[kk][ty * 2 + 0];
            float a1 = As[kk][ty * 2 + 1];
            float4 p = *(const float4*)&Ws[kk * 64 + tx * 4];
            float w[4] = { p.x, p.y, p.z, p.w };
#pragma unroll
            for (int cc = 0; cc < 4; cc++) {
                acc[0][cc] += a0 * w[cc];
                acc[1][cc] += a1 * w[cc];
            }
        }
        __syncthreads();
    }
#pragma unroll
    for (int rr = 0; rr < 2; rr++) {
        int row = row0 + ty * 2 + rr;
#pragma unroll
        for (int cc = 0; cc < 4; cc++) {
            int col = tx * 4 + cc;
            float ht = tanhf(acc[rr][cc] + bias[col]);
            size_t p = (size_t)row * 64 + col;
            float zz = z[p];
            h[p] = zz * h[p] + (1.f - zz) * ht;
        }
    }
}

// ---------------- projections: rows=4096, cols=128 ([sproj|tproj]), K=64 ----------------
__global__ __launch_bounds__(256) void k_proj(
        const float* __restrict__ h, const float* __restrict__ W1cat,
        const float* __restrict__ b1,
        float* __restrict__ sproj, float* __restrict__ tproj) {
    __shared__ float As[16][33];
    __shared__ float Ws[16 * 128];
    int tid = threadIdx.x;
    int row0 = blockIdx.x * 32;
    const float* hp = h + (size_t)row0 * 64;
    float acc[2][8];
#pragma unroll
    for (int i = 0; i < 2; i++)
#pragma unroll
        for (int j = 0; j < 8; j++) acc[i][j] = 0.f;
    int tx = tid & 15, ty = tid >> 4;
    int lr = tid >> 3;
    int lk = (tid & 7) * 2;
    int wk = tid >> 4;
    int wc = (tid & 15) * 8;
    for (int kt = 0; kt < 4; kt++) {
        int c0 = kt * 16;
        float2 a2 = *(const float2*)&hp[lr * 64 + c0 + lk];
        const float4* wsrc = (const float4*)&W1cat[(size_t)(kt * 16 + wk) * 128 + wc];
        float4 w0 = wsrc[0], w1 = wsrc[1];
        As[lk][lr] = a2.x;
        As[lk + 1][lr] = a2.y;
        *(float4*)&Ws[wk * 128 + wc] = w0;
        *(float4*)&Ws[wk * 128 + wc + 4] = w1;
        __syncthreads();
#pragma unroll
        for (int kk = 0; kk < 16; kk++) {
            float a0 = As[kk][ty * 2 + 0];
            float a1 = As[kk][ty * 2 + 1];
            float4 p0 = *(const float4*)&Ws[kk * 128 + tx * 8];
            float4 p1 = *(const float4*)&Ws[kk * 128 + tx * 8 + 4];
            float w[8] = { p0.x, p0.y, p0.z, p0.w, p1.x, p1.y, p1.z, p1.w };
#pragma unroll
            for (int cc = 0; cc < 8; cc++) {
                acc[0][cc] += a0 * w[cc];
                acc[1][cc] += a1 * w[cc];
            }
        }
        __syncthreads();
    }
#pragma unroll
    for (int rr = 0; rr < 2; rr++) {
        int row = row0 + ty * 2 + rr;
#pragma unroll
        for (int cc = 0; cc < 8; cc++) {
            int col = tx * 8 + cc;
            float v = acc[rr][cc];
            if (col < 64) sproj[(size_t)row * 64 + col] = v + b1[col];
            else tproj[(size_t)row * 64 + (col - 64)] = v;
        }
    }
}

// ---------------- logits: out[b,s,t] = sum_h relu(sp[s,h]+tp[t,h])*W2[h] + b2 ----------------
// grid = 8 * 16 * 8 (b, s-tile of 32, t-tile of 64), block=256
__global__ __launch_bounds__(256) void k_logits(
        const float* __restrict__ sproj, const float* __restrict__ tproj,
        const float* __restrict__ W2, const float* __restrict__ b2,
        float* __restrict__ out) {
    __shared__ float sp[32 * 64];
    __shared__ float tp[64 * 65];
    __shared__ float w2s[64];
    int tid = threadIdx.x;
    int bb = blockIdx.x >> 7;
    int st = (blockIdx.x >> 3) & 15;
    int tt = blockIdx.x & 7;
    const float* spg = sproj + ((size_t)bb * Nn + st * 32) * 64;
    const float* tpg = tproj + ((size_t)bb * Nn + tt * 64) * 64;
    for (int i = tid; i < 2048; i += 256) sp[i] = spg[i];
    for (int i = tid; i < 4096; i += 256) {
        int tl = i >> 6, hh = i & 63;
        tp[tl * 65 + hh] = tpg[i];
    }
    if (tid < 64) w2s[tid] = W2[tid];
    __syncthreads();
    float bias = *b2;
    int tl = tid & 63, sg = tid >> 6;
    for (int si = 0; si < 8; si++) {
        int s = sg * 8 + si;
        float acc = bias;
#pragma unroll 8
        for (int hh = 0; hh < 64; hh++) {
            float v = sp[s * 64 + hh] + tp[tl * 65 + hh];
            acc += fmaxf(v, 0.f) * w2s[hh];
        }
        out[(size_t)bb * Nn * Nn + (size_t)(st * 32 + s) * Nn + tt * 64 + tl] = acc;
    }
}

// ---------------- host ----------------
extern "C" void kernel_launch(void* const* d_in, const int* in_sizes, int n_in,
                              void* d_out, int out_size, void* d_ws, size_t ws_size,
                              hipStream_t stream) {
    const float* x  = (const float*)d_in[0];
    const float* ew = (const float*)d_in[1];
    const float* Wx = (const float*)d_in[2];
    const float* bx = (const float*)d_in[3];
    const float* Wh = (const float*)d_in[4];
    const float* bh = (const float*)d_in[5];
    const float* W1 = (const float*)d_in[6];
    const float* b1 = (const float*)d_in[7];
    const float* W2 = (const float*)d_in[8];
    const float* b2 = (const float*)d_in[9];
    const int* ei   = (const int*)d_in[10];
    const int* esrc = ei;
    const int* edst = ei + En;

    float* ws = (float*)d_ws;
    float* deg   = ws + OFF_DEG;
    float* dinv  = ws + OFF_DINV;
    float* nw    = ws + OFF_NW;
    float* csr_w = ws + OFF_CSRW;
    int* iarea   = (int*)(ws + OFF_INT);
    int* counts  = iarea + INT_COUNTS;
    int* cursor  = iarea + INT_CURSOR;
    int* csr_off = iarea + INT_CSROFF;
    int* csr_src = iarea + INT_CSRSRC;
    float* WzrC  = ws + OFF_WZR;
    float* WhC   = ws + OFF_WHT;
    float* bzr   = ws + OFF_BZR;
    float* bht   = ws + OFF_BHT;
    float* W1cat = ws + OFF_W1C;
    float* T1x   = ws + OFF_T1X;
    float* T2x   = ws + OFF_T2X;
    float* h     = ws + OFF_H;
    float* u1    = ws + OFF_U1;
    float* u2    = ws + OFF_U2;
    float* z     = ws + OFF_Z;
    float* hr    = ws + OFF_HR;
    float* v1    = ws + OFF_V1;
    float* v2    = ws + OFF_V2;
    float* sproj = ws + OFF_SP;
    float* tproj = ws + OFF_TP;
    float* out   = (float*)d_out;

    // zero-init accumulators (ws is poisoned each call)
    hipMemsetAsync(deg, 0, 512 * sizeof(float), stream);
    hipMemsetAsync(counts, 0, 512 * sizeof(int), stream);
    hipMemsetAsync(h, 0, (size_t)Bn * NC * sizeof(float), stream);

    k_deg<<<64, 256, 0, stream>>>(ew, esrc, deg);
    k_dinv<<<2, 256, 0, stream>>>(deg, dinv);
    k_normw<<<64, 256, 0, stream>>>(ew, esrc, edst, dinv, nw, counts);
    k_scan<<<1, 512, 0, stream>>>(counts, csr_off, cursor);
    k_fill<<<64, 256, 0, stream>>>(esrc, edst, nw, cursor, csr_src, csr_w);
    k_repack<<<(156032 + 255) / 256, 256, 0, stream>>>(Wx, bx, Wh, bh, W1,
                                                       WzrC, WhC, bzr, bht, W1cat);

    // Chebyshev polys of x for all (b,t): T1x = Lx(x); T2x = 2*Lx(T1x) - x
    k_gather<<<Bn * Tn * 16, 256, 0, stream>>>(x, x, T1x, csr_off, csr_src, csr_w, 1.f, 0.f);
    k_gather<<<Bn * Tn * 16, 256, 0, stream>>>(T1x, x, T2x, csr_off, csr_src, csr_w, 2.f, -1.f);

    // recurrence
    for (int t = 0; t < Tn; t++) {
        for (int l = 0; l < Ln; l++) {
            k_gather<<<Bn * 16, 256, 0, stream>>>(h, h, u1, csr_off, csr_src, csr_w, 1.f, 0.f);
            k_gather<<<Bn * 16, 256, 0, stream>>>(u1, h, u2, csr_off, csr_src, csr_w, 2.f, -1.f);
            k_zr<<<128, 256, 0, stream>>>(h, u1, u2, x, T1x, T2x,
                                          WzrC + (size_t)l * 384 * 128, bzr + l * 128,
                                          z, hr, t);
            k_gather<<<Bn * 16, 256, 0, stream>>>(hr, hr, v1, csr_off, csr_src, csr_w, 1.f, 0.f);
            k_gather<<<Bn * 16, 256, 0, stream>>>(v1, hr, v2, csr_off, csr_src, csr_w, 2.f, -1.f);
            k_ht<<<128, 256, 0, stream>>>(hr, v1, v2, x, T1x, T2x,
                                          WhC + (size_t)l * 384 * 64, bht + l * 64,
                                          z, h, t);
        }
    }

    // predictor
    k_proj<<<128, 256, 0, stream>>>(h, W1cat, b1, sproj, tproj);
    k_logits<<<Bn * 16 * 8, 256, 0, stream>>>(sproj, tproj, W2, b2, out);
}

// Round 2
// 5028.848 us; speedup vs baseline: 2.3902x; 2.3902x over previous
//
#include <hip/hip_runtime.h>

// Problem constants
constexpr int Bn = 8, Tn = 16, Nn = 512, Cn = 64, Hn = 64, En = 16384, Ln = 2;
constexpr int NC = Nn * Cn;           // 32768
constexpr int MROWS = Bn * Nn;        // 4096

// ---------------- workspace layout (in floats) ----------------
constexpr size_t OFF_DEG  = 0;                            // 512
constexpr size_t OFF_DINV = 512;                          // 512
constexpr size_t OFF_L1D  = 1024;                         // 512*512
constexpr size_t OFF_L2D  = OFF_L1D + 262144;             // 512*512
constexpr size_t OFF_WZR  = OFF_L2D + 262144;             // 2*384*128
constexpr size_t OFF_WHT  = OFF_WZR + 2*384*128;          // 2*384*64
constexpr size_t OFF_BZR  = OFF_WHT + 2*384*64;           // 256
constexpr size_t OFF_BHT  = OFF_BZR + 256;                // 128
constexpr size_t OFF_W1C  = OFF_BHT + 128;                // 8192
constexpr size_t OFF_T1X  = OFF_W1C + 8192;               // B*T*N*C
constexpr size_t OFF_T2X  = OFF_T1X + (size_t)Bn*Tn*NC;
constexpr size_t OFF_H    = OFF_T2X + (size_t)Bn*Tn*NC;   // B*N*H
constexpr size_t OFF_Z    = OFF_H   + (size_t)Bn*NC;
constexpr size_t OFF_HR   = OFF_Z   + (size_t)Bn*NC;
constexpr size_t OFF_SP   = OFF_HR  + (size_t)Bn*NC;
constexpr size_t OFF_TP   = OFF_SP  + (size_t)MROWS*Hn;
constexpr size_t OFF_END  = OFF_TP  + (size_t)MROWS*Hn;   // ~10.4M floats ~41.5MB

// ---------------- setup kernels ----------------
__global__ void k_deg(const float* __restrict__ w, const int* __restrict__ src,
                      float* __restrict__ deg) {
    int e = blockIdx.x * 256 + threadIdx.x;
    if (e < En) atomicAdd(&deg[src[e]], w[e]);
}

__global__ void k_dinv(const float* __restrict__ deg, float* __restrict__ dinv) {
    int n = blockIdx.x * 256 + threadIdx.x;
    if (n < Nn) {
        float d = deg[n];
        dinv[n] = d > 0.f ? rsqrtf(fmaxf(d, 1e-12f)) : 0.f;
    }
}

// build dense L1[dst][src] += norm_w
__global__ void k_nwdense(const float* __restrict__ w, const int* __restrict__ src,
                          const int* __restrict__ dst, const float* __restrict__ dinv,
                          float* __restrict__ L1d) {
    int e = blockIdx.x * 256 + threadIdx.x;
    if (e < En) {
        int s = src[e], d = dst[e];
        float nw = -w[e] * dinv[s] * dinv[d];
        atomicAdd(&L1d[d * Nn + s], nw);
    }
}

// L2 = 2*(L1@L1) - I   (512x512, K=512)
__global__ __launch_bounds__(256) void k_l2(const float* __restrict__ A,
                                            float* __restrict__ C) {
    __shared__ float As[64][33];
    __shared__ float Bs[32][65];
    int t = threadIdx.x;
    int i0 = (blockIdx.x >> 3) * 64;
    int j0 = (blockIdx.x & 7) * 64;
    int tx = t & 15, ty = t >> 4;
    float acc[4][4] = {};
    int ar = t >> 2, ac = (t & 3) * 8;
    int br = t >> 3, bc = (t & 7) * 8;
    for (int kc = 0; kc < 512; kc += 32) {
        float4 a0 = *(const float4*)&A[(size_t)(i0 + ar) * 512 + kc + ac];
        float4 a1 = *(const float4*)&A[(size_t)(i0 + ar) * 512 + kc + ac + 4];
        float4 b0 = *(const float4*)&A[(size_t)(kc + br) * 512 + j0 + bc];
        float4 b1 = *(const float4*)&A[(size_t)(kc + br) * 512 + j0 + bc + 4];
        As[ar][ac+0]=a0.x; As[ar][ac+1]=a0.y; As[ar][ac+2]=a0.z; As[ar][ac+3]=a0.w;
        As[ar][ac+4]=a1.x; As[ar][ac+5]=a1.y; As[ar][ac+6]=a1.z; As[ar][ac+7]=a1.w;
        Bs[br][bc+0]=b0.x; Bs[br][bc+1]=b0.y; Bs[br][bc+2]=b0.z; Bs[br][bc+3]=b0.w;
        Bs[br][bc+4]=b1.x; Bs[br][bc+5]=b1.y; Bs[br][bc+6]=b1.z; Bs[br][bc+7]=b1.w;
        __syncthreads();
#pragma unroll 8
        for (int kk = 0; kk < 32; kk++) {
            float av[4], bv[4];
#pragma unroll
            for (int r = 0; r < 4; r++) av[r] = As[ty * 4 + r][kk];
#pragma unroll
            for (int c = 0; c < 4; c++) bv[c] = Bs[kk][tx * 4 + c];
#pragma unroll
            for (int r = 0; r < 4; r++)
#pragma unroll
                for (int c = 0; c < 4; c++) acc[r][c] += av[r] * bv[c];
        }
        __syncthreads();
    }
#pragma unroll
    for (int r = 0; r < 4; r++)
#pragma unroll
        for (int c = 0; c < 4; c++) {
            int i = i0 + ty * 4 + r, j = j0 + tx * 4 + c;
            C[(size_t)i * 512 + j] = 2.f * acc[r][c] - (i == j ? 1.f : 0.f);
        }
}

// out[slice] = L @ in[slice]  (per 128 slices, 64-row tiles, K=512, 64 cols)
__global__ __launch_bounds__(256) void k_lmm(const float* __restrict__ L,
        const float* __restrict__ in, float* __restrict__ out) {
    int slice = blockIdx.x >> 3;
    int n0 = (blockIdx.x & 7) * 64;
    const float* xs = in + (size_t)slice * NC;
    float* os = out + (size_t)slice * NC;
    __shared__ float As[64][33];
    __shared__ float Bs[32][65];
    int t = threadIdx.x;
    int tx = t & 15, ty = t >> 4;
    float acc[4][4] = {};
    int ar = t >> 2, ac = (t & 3) * 8;
    int br = t >> 3, bc = (t & 7) * 8;
    for (int kc = 0; kc < 512; kc += 32) {
        float4 a0 = *(const float4*)&L[(size_t)(n0 + ar) * 512 + kc + ac];
        float4 a1 = *(const float4*)&L[(size_t)(n0 + ar) * 512 + kc + ac + 4];
        float4 b0 = *(const float4*)&xs[(size_t)(kc + br) * 64 + bc];
        float4 b1 = *(const float4*)&xs[(size_t)(kc + br) * 64 + bc + 4];
        As[ar][ac+0]=a0.x; As[ar][ac+1]=a0.y; As[ar][ac+2]=a0.z; As[ar][ac+3]=a0.w;
        As[ar][ac+4]=a1.x; As[ar][ac+5]=a1.y; As[ar][ac+6]=a1.z; As[ar][ac+7]=a1.w;
        Bs[br][bc+0]=b0.x; Bs[br][bc+1]=b0.y; Bs[br][bc+2]=b0.z; Bs[br][bc+3]=b0.w;
        Bs[br][bc+4]=b1.x; Bs[br][bc+5]=b1.y; Bs[br][bc+6]=b1.z; Bs[br][bc+7]=b1.w;
        __syncthreads();
#pragma unroll 8
        for (int kk = 0; kk < 32; kk++) {
            float av[4], bv[4];
#pragma unroll
            for (int r = 0; r < 4; r++) av[r] = As[ty * 4 + r][kk];
#pragma unroll
            for (int c = 0; c < 4; c++) bv[c] = Bs[kk][tx * 4 + c];
#pragma unroll
            for (int r = 0; r < 4; r++)
#pragma unroll
                for (int c = 0; c < 4; c++) acc[r][c] += av[r] * bv[c];
        }
        __syncthreads();
    }
#pragma unroll
    for (int r = 0; r < 4; r++)
#pragma unroll
        for (int c = 0; c < 4; c++)
            os[(size_t)(n0 + ty * 4 + r) * 64 + tx * 4 + c] = acc[r][c];
}

// repack weights: WzrC[l][384][128], WhC[l][384][64], bzr[l][128], bht[l][64], W1cat[64][128]
__global__ void k_repack(const float* __restrict__ Wx, const float* __restrict__ bx,
                         const float* __restrict__ Wh, const float* __restrict__ bh,
                         const float* __restrict__ W1,
                         float* __restrict__ WzrC, float* __restrict__ WhC,
                         float* __restrict__ bzr, float* __restrict__ bht,
                         float* __restrict__ W1cat) {
    int idx = blockIdx.x * 256 + threadIdx.x;
    if (idx < 98304) {
        int l = idx / 49152, r = idx % 49152;
        int k = r / 128, j = r % 128;
        int g = j >> 6, hh = j & 63;
        int kc, c; const float* s;
        if (k < 192) { kc = k / 64; c = k % 64; s = Wh; }
        else { kc = (k - 192) / 64; c = (k - 192) % 64; s = Wx; }
        WzrC[idx] = s[((((size_t)(l*3 + g))*3 + kc)*64 + c)*64 + hh];
    } else if (idx < 147456) {
        int tI = idx - 98304;
        int l = tI / 24576, r = tI % 24576;
        int k = r / 64, hh = r % 64;
        int kc, c; const float* s;
        if (k < 192) { kc = k / 64; c = k % 64; s = Wh; }
        else { kc = (k - 192) / 64; c = (k - 192) % 64; s = Wx; }
        WhC[tI] = s[((((size_t)(l*3 + 2))*3 + kc)*64 + c)*64 + hh];
    } else if (idx < 147712) {
        int tI = idx - 147456;
        int l = tI >> 7, j = tI & 127;
        int g = j >> 6, hh = j & 63;
        bzr[tI] = bh[(l*3 + g)*64 + hh] + bx[(l*3 + g)*64 + hh];
    } else if (idx < 147840) {
        int tI = idx - 147712;
        int l = tI >> 6, hh = tI & 63;
        bht[tI] = bh[(l*3 + 2)*64 + hh] + bx[(l*3 + 2)*64 + hh];
    } else if (idx < 156032) {
        int tI = idx - 147840;
        int c = tI >> 7, j = tI & 127;
        W1cat[tI] = (j < 64) ? W1[c*64 + j] : W1[(64 + c)*64 + (j - 64)];
    }
}

// ---------------- fused cell stage 1: u1,u2 then z,r GEMM then hr ----------------
// grid = B*16 (32-node tiles), block = 256
__global__ __launch_bounds__(256) void k_cell1(
        const float* __restrict__ h, const float* __restrict__ x,
        const float* __restrict__ t1x, const float* __restrict__ t2x,
        const float* __restrict__ L1, const float* __restrict__ L2,
        const float* __restrict__ W, const float* __restrict__ bias,
        float* __restrict__ z, float* __restrict__ hr, int t) {
    __shared__ float Hs[32][65];
    __shared__ float L1s[32][33], L2s[32][33];
    __shared__ float U1s[32][65], U2s[32][65];
    __shared__ float As[16][33];
    __shared__ float Ws[16 * 128];
    int tid = threadIdx.x;
    int b = blockIdx.x >> 4;
    int n0 = (blockIdx.x & 15) * 32;
    const float* hb = h + (size_t)b * NC;

    // phase A: U1 = L1[tile,:]@h_b, U2 = L2[tile,:]@h_b  (M=32,N=64,K=512)
    int r = tid >> 3, c0 = (tid & 7) * 8;
    int lc = (tid & 7) * 4;
    float acc1[8] = {}, acc2[8] = {};
    for (int kc = 0; kc < 512; kc += 32) {
        float4 h0 = *(const float4*)&hb[(size_t)(kc + r) * 64 + c0];
        float4 h1 = *(const float4*)&hb[(size_t)(kc + r) * 64 + c0 + 4];
        float4 l1v = *(const float4*)&L1[(size_t)(n0 + r) * 512 + kc + lc];
        float4 l2v = *(const float4*)&L2[(size_t)(n0 + r) * 512 + kc + lc];
        Hs[r][c0+0]=h0.x; Hs[r][c0+1]=h0.y; Hs[r][c0+2]=h0.z; Hs[r][c0+3]=h0.w;
        Hs[r][c0+4]=h1.x; Hs[r][c0+5]=h1.y; Hs[r][c0+6]=h1.z; Hs[r][c0+7]=h1.w;
        L1s[r][lc+0]=l1v.x; L1s[r][lc+1]=l1v.y; L1s[r][lc+2]=l1v.z; L1s[r][lc+3]=l1v.w;
        L2s[r][lc+0]=l2v.x; L2s[r][lc+1]=l2v.y; L2s[r][lc+2]=l2v.z; L2s[r][lc+3]=l2v.w;
        __syncthreads();
#pragma unroll 8
        for (int kk = 0; kk < 32; kk++) {
            float a1 = L1s[r][kk], a2 = L2s[r][kk];
#pragma unroll
            for (int j = 0; j < 8; j++) {
                float hv = Hs[kk][c0 + j];
                acc1[j] += a1 * hv;
                acc2[j] += a2 * hv;
            }
        }
        __syncthreads();
    }
#pragma unroll
    for (int j = 0; j < 8; j++) { U1s[r][c0 + j] = acc1[j]; U2s[r][c0 + j] = acc2[j]; }
    __syncthreads();

    // phase B: zr = [h, u1, u2, x, t1x, t2x] @ W  (M=32, N=128, K=384)
    size_t hoff = ((size_t)b * Nn + n0) * 64;
    size_t xoff = ((size_t)(b * Tn + t) * Nn + n0) * 64;
    const float* g0 = h + hoff;
    const float* g3 = x + xoff;
    const float* g4 = t1x + xoff;
    const float* g5 = t2x + xoff;
    float acc[2][8] = {};
    int tx = tid & 15, ty = tid >> 4;
    int lr = tid >> 3, lk = (tid & 7) * 2;
    int wk = tid >> 4, wc = (tid & 15) * 8;
    for (int kt = 0; kt < 24; kt++) {
        int s = kt >> 2, cc = (kt & 3) * 16;
        float a0v, a1v;
        if (s == 1)      { a0v = U1s[lr][cc + lk]; a1v = U1s[lr][cc + lk + 1]; }
        else if (s == 2) { a0v = U2s[lr][cc + lk]; a1v = U2s[lr][cc + lk + 1]; }
        else {
            const float* gp = (s == 0) ? g0 : (s == 3) ? g3 : (s == 4) ? g4 : g5;
            float2 a2 = *(const float2*)&gp[lr * 64 + cc + lk];
            a0v = a2.x; a1v = a2.y;
        }
        const float4* wsrc = (const float4*)&W[(size_t)(kt * 16 + wk) * 128 + wc];
        float4 w0 = wsrc[0], w1 = wsrc[1];
        As[lk][lr] = a0v;
        As[lk + 1][lr] = a1v;
        *(float4*)&Ws[wk * 128 + wc] = w0;
        *(float4*)&Ws[wk * 128 + wc + 4] = w1;
        __syncthreads();
#pragma unroll
        for (int kk = 0; kk < 16; kk++) {
            float a0 = As[kk][ty * 2 + 0];
            float a1 = As[kk][ty * 2 + 1];
            float4 p0 = *(const float4*)&Ws[kk * 128 + tx * 8];
            float4 p1 = *(const float4*)&Ws[kk * 128 + tx * 8 + 4];
            float w[8] = { p0.x, p0.y, p0.z, p0.w, p1.x, p1.y, p1.z, p1.w };
#pragma unroll
            for (int ccx = 0; ccx < 8; ccx++) {
                acc[0][ccx] += a0 * w[ccx];
                acc[1][ccx] += a1 * w[ccx];
            }
        }
        __syncthreads();
    }
#pragma unroll
    for (int rr = 0; rr < 2; rr++) {
        int grow = b * Nn + n0 + ty * 2 + rr;
#pragma unroll
        for (int ccx = 0; ccx < 8; ccx++) {
            int col = tx * 8 + ccx;
            float v = acc[rr][ccx] + bias[col];
            float sgm = 1.f / (1.f + __expf(-v));
            if (col < 64) {
                z[(size_t)grow * 64 + col] = sgm;
            } else {
                size_t p = (size_t)grow * 64 + (col - 64);
                hr[p] = h[p] * sgm;
            }
        }
    }
}

// ---------------- fused cell stage 2: v1,v2 then h_tilde GEMM then GRU update ----------------
__global__ __launch_bounds__(256) void k_cell2(
        const float* __restrict__ hr, const float* __restrict__ x,
        const float* __restrict__ t1x, const float* __restrict__ t2x,
        const float* __restrict__ L1, const float* __restrict__ L2,
        const float* __restrict__ W, const float* __restrict__ bias,
        const float* __restrict__ z, float* __restrict__ h, int t) {
    __shared__ float Hs[32][65];
    __shared__ float L1s[32][33], L2s[32][33];
    __shared__ float U1s[32][65], U2s[32][65];
    __shared__ float As[16][33];
    __shared__ float Ws[16 * 64];
    int tid = threadIdx.x;
    int b = blockIdx.x >> 4;
    int n0 = (blockIdx.x & 15) * 32;
    const float* hb = hr + (size_t)b * NC;

    int r = tid >> 3, c0 = (tid & 7) * 8;
    int lc = (tid & 7) * 4;
    float acc1[8] = {}, acc2[8] = {};
    for (int kc = 0; kc < 512; kc += 32) {
        float4 h0 = *(const float4*)&hb[(size_t)(kc + r) * 64 + c0];
        float4 h1 = *(const float4*)&hb[(size_t)(kc + r) * 64 + c0 + 4];
        float4 l1v = *(const float4*)&L1[(size_t)(n0 + r) * 512 + kc + lc];
        float4 l2v = *(const float4*)&L2[(size_t)(n0 + r) * 512 + kc + lc];
        Hs[r][c0+0]=h0.x; Hs[r][c0+1]=h0.y; Hs[r][c0+2]=h0.z; Hs[r][c0+3]=h0.w;
        Hs[r][c0+4]=h1.x; Hs[r][c0+5]=h1.y; Hs[r][c0+6]=h1.z; Hs[r][c0+7]=h1.w;
        L1s[r][lc+0]=l1v.x; L1s[r][lc+1]=l1v.y; L1s[r][lc+2]=l1v.z; L1s[r][lc+3]=l1v.w;
        L2s[r][lc+0]=l2v.x; L2s[r][lc+1]=l2v.y; L2s[r][lc+2]=l2v.z; L2s[r][lc+3]=l2v.w;
        __syncthreads();
#pragma unroll 8
        for (int kk = 0; kk < 32; kk++) {
            float a1 = L1s[r][kk], a2 = L2s[r][kk];
#pragma unroll
            for (int j = 0; j < 8; j++) {
                float hv = Hs[kk][c0 + j];
                acc1[j] += a1 * hv;
                acc2[j] += a2 * hv;
            }
        }
        __syncthreads();
    }
#pragma unroll
    for (int j = 0; j < 8; j++) { U1s[r][c0 + j] = acc1[j]; U2s[r][c0 + j] = acc2[j]; }
    __syncthreads();

    size_t hoff = ((size_t)b * Nn + n0) * 64;
    size_t xoff = ((size_t)(b * Tn + t) * Nn + n0) * 64;
    const float* g0 = hr + hoff;
    const float* g3 = x + xoff;
    const float* g4 = t1x + xoff;
    const float* g5 = t2x + xoff;
    float acc[2][4] = {};
    int tx = tid & 15, ty = tid >> 4;
    int lr = tid >> 3, lk = (tid & 7) * 2;
    int wk = tid >> 4, wc = (tid & 15) * 4;
    for (int kt = 0; kt < 24; kt++) {
        int s = kt >> 2, cc = (kt & 3) * 16;
        float a0v, a1v;
        if (s == 1)      { a0v = U1s[lr][cc + lk]; a1v = U1s[lr][cc + lk + 1]; }
        else if (s == 2) { a0v = U2s[lr][cc + lk]; a1v = U2s[lr][cc + lk + 1]; }
        else {
            const float* gp = (s == 0) ? g0 : (s == 3) ? g3 : (s == 4) ? g4 : g5;
            float2 a2 = *(const float2*)&gp[lr * 64 + cc + lk];
            a0v = a2.x; a1v = a2.y;
        }
        float4 w0 = *(const float4*)&W[(size_t)(kt * 16 + wk) * 64 + wc];
        As[lk][lr] = a0v;
        As[lk + 1][lr] = a1v;
        *(float4*)&Ws[wk * 64 + wc] = w0;
        __syncthreads();
#pragma unroll
        for (int kk = 0; kk < 16; kk++) {
            float a0 = As[kk][ty * 2 + 0];
            float a1 = As[kk][ty * 2 + 1];
            float4 p = *(const float4*)&Ws[kk * 64 + tx * 4];
            float w[4] = { p.x, p.y, p.z, p.w };
#pragma unroll
            for (int ccx = 0; ccx < 4; ccx++) {
                acc[0][ccx] += a0 * w[ccx];
                acc[1][ccx] += a1 * w[ccx];
            }
        }
        __syncthreads();
    }
#pragma unroll
    for (int rr = 0; rr < 2; rr++) {
        int grow = b * Nn + n0 + ty * 2 + rr;
#pragma unroll
        for (int ccx = 0; ccx < 4; ccx++) {
            int col = tx * 4 + ccx;
            float htv = tanhf(acc[rr][ccx] + bias[col]);
            size_t p = (size_t)grow * 64 + col;
            float zz = z[p];
            h[p] = zz * h[p] + (1.f - zz) * htv;
        }
    }
}

// ---------------- projections: rows=4096, cols=128 ([sproj|tproj]), K=64 ----------------
__global__ __launch_bounds__(256) void k_proj(
        const float* __restrict__ h, const float* __restrict__ W1cat,
        const float* __restrict__ b1,
        float* __restrict__ sproj, float* __restrict__ tproj) {
    __shared__ float As[16][33];
    __shared__ float Ws[16 * 128];
    int tid = threadIdx.x;
    int row0 = blockIdx.x * 32;
    const float* hp = h + (size_t)row0 * 64;
    float acc[2][8] = {};
    int tx = tid & 15, ty = tid >> 4;
    int lr = tid >> 3;
    int lk = (tid & 7) * 2;
    int wk = tid >> 4;
    int wc = (tid & 15) * 8;
    for (int kt = 0; kt < 4; kt++) {
        int c0 = kt * 16;
        float2 a2 = *(const float2*)&hp[lr * 64 + c0 + lk];
        const float4* wsrc = (const float4*)&W1cat[(size_t)(kt * 16 + wk) * 128 + wc];
        float4 w0 = wsrc[0], w1 = wsrc[1];
        As[lk][lr] = a2.x;
        As[lk + 1][lr] = a2.y;
        *(float4*)&Ws[wk * 128 + wc] = w0;
        *(float4*)&Ws[wk * 128 + wc + 4] = w1;
        __syncthreads();
#pragma unroll
        for (int kk = 0; kk < 16; kk++) {
            float a0 = As[kk][ty * 2 + 0];
            float a1 = As[kk][ty * 2 + 1];
            float4 p0 = *(const float4*)&Ws[kk * 128 + tx * 8];
            float4 p1 = *(const float4*)&Ws[kk * 128 + tx * 8 + 4];
            float w[8] = { p0.x, p0.y, p0.z, p0.w, p1.x, p1.y, p1.z, p1.w };
#pragma unroll
            for (int cc = 0; cc < 8; cc++) {
                acc[0][cc] += a0 * w[cc];
                acc[1][cc] += a1 * w[cc];
            }
        }
        __syncthreads();
    }
#pragma unroll
    for (int rr = 0; rr < 2; rr++) {
        int row = row0 + ty * 2 + rr;
#pragma unroll
        for (int cc = 0; cc < 8; cc++) {
            int col = tx * 8 + cc;
            float v = acc[rr][cc];
            if (col < 64) sproj[(size_t)row * 64 + col] = v + b1[col];
            else tproj[(size_t)row * 64 + (col - 64)] = v;
        }
    }
}

// ---------------- logits ----------------
__global__ __launch_bounds__(256) void k_logits(
        const float* __restrict__ sproj, const float* __restrict__ tproj,
        const float* __restrict__ W2, const float* __restrict__ b2,
        float* __restrict__ out) {
    __shared__ float sp[32 * 64];
    __shared__ float tp[64 * 65];
    __shared__ float w2s[64];
    int tid = threadIdx.x;
    int bb = blockIdx.x >> 7;
    int st = (blockIdx.x >> 3) & 15;
    int tt = blockIdx.x & 7;
    const float* spg = sproj + ((size_t)bb * Nn + st * 32) * 64;
    const float* tpg = tproj + ((size_t)bb * Nn + tt * 64) * 64;
    for (int i = tid; i < 2048; i += 256) sp[i] = spg[i];
    for (int i = tid; i < 4096; i += 256) {
        int tl = i >> 6, hh = i & 63;
        tp[tl * 65 + hh] = tpg[i];
    }
    if (tid < 64) w2s[tid] = W2[tid];
    __syncthreads();
    float bias = *b2;
    int tl = tid & 63, sg = tid >> 6;
    for (int si = 0; si < 8; si++) {
        int s = sg * 8 + si;
        float acc = bias;
#pragma unroll 8
        for (int hh = 0; hh < 64; hh++) {
            float v = sp[s * 64 + hh] + tp[tl * 65 + hh];
            acc += fmaxf(v, 0.f) * w2s[hh];
        }
        out[(size_t)bb * Nn * Nn + (size_t)(st * 32 + s) * Nn + tt * 64 + tl] = acc;
    }
}

// ---------------- host ----------------
extern "C" void kernel_launch(void* const* d_in, const int* in_sizes, int n_in,
                              void* d_out, int out_size, void* d_ws, size_t ws_size,
                              hipStream_t stream) {
    const float* x  = (const float*)d_in[0];
    const float* ew = (const float*)d_in[1];
    const float* Wx = (const float*)d_in[2];
    const float* bx = (const float*)d_in[3];
    const float* Wh = (const float*)d_in[4];
    const float* bh = (const float*)d_in[5];
    const float* W1 = (const float*)d_in[6];
    const float* b1 = (const float*)d_in[7];
    const float* W2 = (const float*)d_in[8];
    const float* b2 = (const float*)d_in[9];
    const int* ei   = (const int*)d_in[10];
    const int* esrc = ei;
    const int* edst = ei + En;

    float* ws = (float*)d_ws;
    float* deg   = ws + OFF_DEG;
    float* dinv  = ws + OFF_DINV;
    float* L1d   = ws + OFF_L1D;
    float* L2d   = ws + OFF_L2D;
    float* WzrC  = ws + OFF_WZR;
    float* WhC   = ws + OFF_WHT;
    float* bzr   = ws + OFF_BZR;
    float* bht   = ws + OFF_BHT;
    float* W1cat = ws + OFF_W1C;
    float* T1x   = ws + OFF_T1X;
    float* T2x   = ws + OFF_T2X;
    float* h     = ws + OFF_H;
    float* z     = ws + OFF_Z;
    float* hr    = ws + OFF_HR;
    float* sproj = ws + OFF_SP;
    float* tproj = ws + OFF_TP;
    float* out   = (float*)d_out;

    hipMemsetAsync(deg, 0, 512 * sizeof(float), stream);
    hipMemsetAsync(L1d, 0, (size_t)Nn * Nn * sizeof(float), stream);
    hipMemsetAsync(h, 0, (size_t)Bn * NC * sizeof(float), stream);

    k_deg<<<64, 256, 0, stream>>>(ew, esrc, deg);
    k_dinv<<<2, 256, 0, stream>>>(deg, dinv);
    k_nwdense<<<64, 256, 0, stream>>>(ew, esrc, edst, dinv, L1d);
    k_l2<<<64, 256, 0, stream>>>(L1d, L2d);
    k_repack<<<(156032 + 255) / 256, 256, 0, stream>>>(Wx, bx, Wh, bh, W1,
                                                       WzrC, WhC, bzr, bht, W1cat);

    // Chebyshev polys of x: T1x = L1 @ x ; T2x = (2L^2 - I) @ x — independent
    k_lmm<<<Bn * Tn * 8, 256, 0, stream>>>(L1d, x, T1x);
    k_lmm<<<Bn * Tn * 8, 256, 0, stream>>>(L2d, x, T2x);

    // recurrence: 2 fused kernels per GRU cell
    for (int t = 0; t < Tn; t++) {
        for (int l = 0; l < Ln; l++) {
            k_cell1<<<Bn * 16, 256, 0, stream>>>(h, x, T1x, T2x, L1d, L2d,
                                                 WzrC + (size_t)l * 384 * 128,
                                                 bzr + l * 128, z, hr, t);
            k_cell2<<<Bn * 16, 256, 0, stream>>>(hr, x, T1x, T2x, L1d, L2d,
                                                 WhC + (size_t)l * 384 * 64,
                                                 bht + l * 64, z, h, t);
        }
    }

    k_proj<<<128, 256, 0, stream>>>(h, W1cat, b1, sproj, tproj);
    k_logits<<<Bn * 16 * 8, 256, 0, stream>>>(sproj, tproj, W2, b2, out);
}

// Round 3
// 2572.901 us; speedup vs baseline: 4.6718x; 1.9545x over previous
//
#include <hip/hip_runtime.h>

// Problem constants
constexpr int Bn = 8, Tn = 16, Nn = 512, Cn = 64, Hn = 64, En = 16384, Ln = 2;
constexpr int NC = Nn * Cn;           // 32768
constexpr int MROWS = Bn * Nn;        // 4096

// ---------------- workspace layout (in floats) ----------------
constexpr size_t OFF_DEG  = 0;                            // 512
constexpr size_t OFF_DINV = 512;                          // 512
constexpr size_t OFF_L1D  = 1024;                         // 512*512
constexpr size_t OFF_L2D  = OFF_L1D + 262144;             // 512*512
constexpr size_t OFF_WZR  = OFF_L2D + 262144;             // 2*384*128
constexpr size_t OFF_WHT  = OFF_WZR + 2*384*128;          // 2*384*64
constexpr size_t OFF_BZR  = OFF_WHT + 2*384*64;           // 256
constexpr size_t OFF_BHT  = OFF_BZR + 256;                // 128
constexpr size_t OFF_W1C  = OFF_BHT + 128;                // 8192
constexpr size_t OFF_T1X  = OFF_W1C + 8192;               // B*T*N*C
constexpr size_t OFF_T2X  = OFF_T1X + (size_t)Bn*Tn*NC;
constexpr size_t OFF_H    = OFF_T2X + (size_t)Bn*Tn*NC;   // B*N*H
constexpr size_t OFF_Z    = OFF_H   + (size_t)Bn*NC;
constexpr size_t OFF_HR   = OFF_Z   + (size_t)Bn*NC;
constexpr size_t OFF_SP   = OFF_HR  + (size_t)Bn*NC;
constexpr size_t OFF_TP   = OFF_SP  + (size_t)MROWS*Hn;
constexpr size_t OFF_END  = OFF_TP  + (size_t)MROWS*Hn;   // ~10.4M floats ~41.5MB

// ---------------- setup kernels ----------------
__global__ void k_deg(const float* __restrict__ w, const int* __restrict__ src,
                      float* __restrict__ deg) {
    int e = blockIdx.x * 256 + threadIdx.x;
    if (e < En) atomicAdd(&deg[src[e]], w[e]);
}

__global__ void k_dinv(const float* __restrict__ deg, float* __restrict__ dinv) {
    int n = blockIdx.x * 256 + threadIdx.x;
    if (n < Nn) {
        float d = deg[n];
        dinv[n] = d > 0.f ? rsqrtf(fmaxf(d, 1e-12f)) : 0.f;
    }
}

// build dense L1[dst][src] += norm_w
__global__ void k_nwdense(const float* __restrict__ w, const int* __restrict__ src,
                          const int* __restrict__ dst, const float* __restrict__ dinv,
                          float* __restrict__ L1d) {
    int e = blockIdx.x * 256 + threadIdx.x;
    if (e < En) {
        int s = src[e], d = dst[e];
        float nw = -w[e] * dinv[s] * dinv[d];
        atomicAdd(&L1d[d * Nn + s], nw);
    }
}

// L2 = 2*(L1@L1) - I   (512x512, K=512)
__global__ __launch_bounds__(256) void k_l2(const float* __restrict__ A,
                                            float* __restrict__ C) {
    __shared__ float As[64][33];
    __shared__ float Bs[32][65];
    int t = threadIdx.x;
    int i0 = (blockIdx.x >> 3) * 64;
    int j0 = (blockIdx.x & 7) * 64;
    int tx = t & 15, ty = t >> 4;
    float acc[4][4] = {};
    int ar = t >> 2, ac = (t & 3) * 8;
    int br = t >> 3, bc = (t & 7) * 8;
    for (int kc = 0; kc < 512; kc += 32) {
        float4 a0 = *(const float4*)&A[(size_t)(i0 + ar) * 512 + kc + ac];
        float4 a1 = *(const float4*)&A[(size_t)(i0 + ar) * 512 + kc + ac + 4];
        float4 b0 = *(const float4*)&A[(size_t)(kc + br) * 512 + j0 + bc];
        float4 b1 = *(const float4*)&A[(size_t)(kc + br) * 512 + j0 + bc + 4];
        As[ar][ac+0]=a0.x; As[ar][ac+1]=a0.y; As[ar][ac+2]=a0.z; As[ar][ac+3]=a0.w;
        As[ar][ac+4]=a1.x; As[ar][ac+5]=a1.y; As[ar][ac+6]=a1.z; As[ar][ac+7]=a1.w;
        Bs[br][bc+0]=b0.x; Bs[br][bc+1]=b0.y; Bs[br][bc+2]=b0.z; Bs[br][bc+3]=b0.w;
        Bs[br][bc+4]=b1.x; Bs[br][bc+5]=b1.y; Bs[br][bc+6]=b1.z; Bs[br][bc+7]=b1.w;
        __syncthreads();
#pragma unroll 8
        for (int kk = 0; kk < 32; kk++) {
            float av[4], bv[4];
#pragma unroll
            for (int r = 0; r < 4; r++) av[r] = As[ty * 4 + r][kk];
#pragma unroll
            for (int c = 0; c < 4; c++) bv[c] = Bs[kk][tx * 4 + c];
#pragma unroll
            for (int r = 0; r < 4; r++)
#pragma unroll
                for (int c = 0; c < 4; c++) acc[r][c] += av[r] * bv[c];
        }
        __syncthreads();
    }
#pragma unroll
    for (int r = 0; r < 4; r++)
#pragma unroll
        for (int c = 0; c < 4; c++) {
            int i = i0 + ty * 4 + r, j = j0 + tx * 4 + c;
            C[(size_t)i * 512 + j] = 2.f * acc[r][c] - (i == j ? 1.f : 0.f);
        }
}

// out[slice] = L @ in[slice]
__global__ __launch_bounds__(256) void k_lmm(const float* __restrict__ L,
        const float* __restrict__ in, float* __restrict__ out) {
    int slice = blockIdx.x >> 3;
    int n0 = (blockIdx.x & 7) * 64;
    const float* xs = in + (size_t)slice * NC;
    float* os = out + (size_t)slice * NC;
    __shared__ float As[64][33];
    __shared__ float Bs[32][65];
    int t = threadIdx.x;
    int tx = t & 15, ty = t >> 4;
    float acc[4][4] = {};
    int ar = t >> 2, ac = (t & 3) * 8;
    int br = t >> 3, bc = (t & 7) * 8;
    for (int kc = 0; kc < 512; kc += 32) {
        float4 a0 = *(const float4*)&L[(size_t)(n0 + ar) * 512 + kc + ac];
        float4 a1 = *(const float4*)&L[(size_t)(n0 + ar) * 512 + kc + ac + 4];
        float4 b0 = *(const float4*)&xs[(size_t)(kc + br) * 64 + bc];
        float4 b1 = *(const float4*)&xs[(size_t)(kc + br) * 64 + bc + 4];
        As[ar][ac+0]=a0.x; As[ar][ac+1]=a0.y; As[ar][ac+2]=a0.z; As[ar][ac+3]=a0.w;
        As[ar][ac+4]=a1.x; As[ar][ac+5]=a1.y; As[ar][ac+6]=a1.z; As[ar][ac+7]=a1.w;
        Bs[br][bc+0]=b0.x; Bs[br][bc+1]=b0.y; Bs[br][bc+2]=b0.z; Bs[br][bc+3]=b0.w;
        Bs[br][bc+4]=b1.x; Bs[br][bc+5]=b1.y; Bs[br][bc+6]=b1.z; Bs[br][bc+7]=b1.w;
        __syncthreads();
#pragma unroll 8
        for (int kk = 0; kk < 32; kk++) {
            float av[4], bv[4];
#pragma unroll
            for (int r = 0; r < 4; r++) av[r] = As[ty * 4 + r][kk];
#pragma unroll
            for (int c = 0; c < 4; c++) bv[c] = Bs[kk][tx * 4 + c];
#pragma unroll
            for (int r = 0; r < 4; r++)
#pragma unroll
                for (int c = 0; c < 4; c++) acc[r][c] += av[r] * bv[c];
        }
        __syncthreads();
    }
#pragma unroll
    for (int r = 0; r < 4; r++)
#pragma unroll
        for (int c = 0; c < 4; c++)
            os[(size_t)(n0 + ty * 4 + r) * 64 + tx * 4 + c] = acc[r][c];
}

// repack weights
__global__ void k_repack(const float* __restrict__ Wx, const float* __restrict__ bx,
                         const float* __restrict__ Wh, const float* __restrict__ bh,
                         const float* __restrict__ W1,
                         float* __restrict__ WzrC, float* __restrict__ WhC,
                         float* __restrict__ bzr, float* __restrict__ bht,
                         float* __restrict__ W1cat) {
    int idx = blockIdx.x * 256 + threadIdx.x;
    if (idx < 98304) {
        int l = idx / 49152, r = idx % 49152;
        int k = r / 128, j = r % 128;
        int g = j >> 6, hh = j & 63;
        int kc, c; const float* s;
        if (k < 192) { kc = k / 64; c = k % 64; s = Wh; }
        else { kc = (k - 192) / 64; c = (k - 192) % 64; s = Wx; }
        WzrC[idx] = s[((((size_t)(l*3 + g))*3 + kc)*64 + c)*64 + hh];
    } else if (idx < 147456) {
        int tI = idx - 98304;
        int l = tI / 24576, r = tI % 24576;
        int k = r / 64, hh = r % 64;
        int kc, c; const float* s;
        if (k < 192) { kc = k / 64; c = k % 64; s = Wh; }
        else { kc = (k - 192) / 64; c = (k - 192) % 64; s = Wx; }
        WhC[tI] = s[((((size_t)(l*3 + 2))*3 + kc)*64 + c)*64 + hh];
    } else if (idx < 147712) {
        int tI = idx - 147456;
        int l = tI >> 7, j = tI & 127;
        int g = j >> 6, hh = j & 63;
        bzr[tI] = bh[(l*3 + g)*64 + hh] + bx[(l*3 + g)*64 + hh];
    } else if (idx < 147840) {
        int tI = idx - 147712;
        int l = tI >> 6, hh = tI & 63;
        bht[tI] = bh[(l*3 + 2)*64 + hh] + bx[(l*3 + 2)*64 + hh];
    } else if (idx < 156032) {
        int tI = idx - 147840;
        int c = tI >> 7, j = tI & 127;
        W1cat[tI] = (j < 64) ? W1[c*64 + j] : W1[(64 + c)*64 + (j - 64)];
    }
}

// ================= fused cell kernels, 256 blocks x 16 rows =================
// LDS layout (floats), cell1:
//  HS    @0     [32][68]  = 2176   (h-chunk staging, phase A)
//  L1s   @2176  [16][36]  = 576
//  L2s   @2752  [16][36]  = 576
//  WS    @3328  [16][132] = 2112   (W chunk, phase B)
//  ASEG  @5440  [6][16][64] = 6144 (A-operand segs: h/hr,U1,U2,x,t1x,t2x)
//  PRED aliases lds[0..4095] (k-split partials; only live between phases)

__global__ __launch_bounds__(256) void k_cell1(
        const float* __restrict__ h, const float* __restrict__ x,
        const float* __restrict__ t1x, const float* __restrict__ t2x,
        const float* __restrict__ L1, const float* __restrict__ L2,
        const float* __restrict__ W, const float* __restrict__ bias,
        float* __restrict__ z, float* __restrict__ hr, int t) {
    __shared__ float lds[11584];
    float* HS   = lds;
    float* L1s  = lds + 2176;
    float* L2s  = lds + 2752;
    float* WS   = lds + 3328;
    float* ASEG = lds + 5440;
    float* PRED = lds;

    int tid = threadIdx.x;
    int b = blockIdx.x >> 5;
    int n0 = (blockIdx.x & 31) * 16;
    const float* hb = h + (size_t)b * NC;
    size_t hoff = ((size_t)b * Nn + n0) * 64;
    size_t xoff = ((size_t)(b * Tn + t) * Nn + n0) * 64;

    // stage own-row segments (0=h, 3=x, 4=t1x, 5=t2x); segs 1,2 written by phase A
    {
        int r = tid >> 4, c4 = (tid & 15) * 4;
        *(float4*)&ASEG[0 * 1024 + r * 64 + c4] = *(const float4*)&h[hoff + (size_t)r * 64 + c4];
        *(float4*)&ASEG[3 * 1024 + r * 64 + c4] = *(const float4*)&x[xoff + (size_t)r * 64 + c4];
        *(float4*)&ASEG[4 * 1024 + r * 64 + c4] = *(const float4*)&t1x[xoff + (size_t)r * 64 + c4];
        *(float4*)&ASEG[5 * 1024 + r * 64 + c4] = *(const float4*)&t2x[xoff + (size_t)r * 64 + c4];
    }

    // ---- phase A: U1 = L1[rows,:]@h_b, U2 = L2[rows,:]@h_b, K=512, k-split-2 ----
    int rp = (tid >> 4) & 7, cg = tid & 15, kg = tid >> 7;
    int r0 = rp * 2, r1 = r0 + 1;
    float acc1[2][4] = {}, acc2[2][4] = {};
    int hsr = tid >> 4, hsc = (tid & 15) * 4;
    int llr = (tid & 127) >> 3, llc = (tid & 7) * 4;
    for (int kc = 0; kc < 512; kc += 32) {
        *(float4*)&HS[hsr * 68 + hsc] =
            *(const float4*)&hb[(size_t)(kc + hsr) * 64 + hsc];
        *(float4*)&HS[(hsr + 16) * 68 + hsc] =
            *(const float4*)&hb[(size_t)(kc + hsr + 16) * 64 + hsc];
        {
            const float* Lsrc = (tid < 128) ? L1 : L2;
            float* Ldst = (tid < 128) ? L1s : L2s;
            *(float4*)&Ldst[llr * 36 + llc] =
                *(const float4*)&Lsrc[(size_t)(n0 + llr) * 512 + kc + llc];
        }
        __syncthreads();
#pragma unroll
        for (int kk = 0; kk < 16; kk++) {
            int m = kg * 16 + kk;
            float l1a = L1s[r0 * 36 + m], l1b = L1s[r1 * 36 + m];
            float l2a = L2s[r0 * 36 + m], l2b = L2s[r1 * 36 + m];
            float4 hv = *(const float4*)&HS[m * 68 + cg * 4];
            float hvv[4] = { hv.x, hv.y, hv.z, hv.w };
#pragma unroll
            for (int j = 0; j < 4; j++) {
                acc1[0][j] += l1a * hvv[j];
                acc1[1][j] += l1b * hvv[j];
                acc2[0][j] += l2a * hvv[j];
                acc2[1][j] += l2b * hvv[j];
            }
        }
        __syncthreads();
    }
    // partials -> PRED[((u*2+kg)*16+r)*64+c], reduce into ASEG[1],[2]
#pragma unroll
    for (int rr = 0; rr < 2; rr++)
#pragma unroll
        for (int j = 0; j < 4; j++) {
            PRED[((0 * 2 + kg) * 16 + r0 + rr) * 64 + cg * 4 + j] = acc1[rr][j];
            PRED[((1 * 2 + kg) * 16 + r0 + rr) * 64 + cg * 4 + j] = acc2[rr][j];
        }
    __syncthreads();
    for (int i = tid; i < 2048; i += 256) {
        int u = i >> 10, rc = i & 1023;
        ASEG[(1 + u) * 1024 + rc] = PRED[(u * 2 + 0) * 1024 + rc] + PRED[(u * 2 + 1) * 1024 + rc];
    }
    __syncthreads();

    // ---- phase B: zr[16][128] = A[16][384] @ W[384][128], k-split-2 ----
    int ty = (tid >> 5) & 3, tx = tid & 31;
    float acc[4][4] = {};
    int wsr = tid >> 4, wsc = (tid & 15) * 8;
    for (int kt = 0; kt < 24; kt++) {
        *(float4*)&WS[wsr * 132 + wsc] = *(const float4*)&W[(size_t)(kt * 16 + wsr) * 128 + wsc];
        *(float4*)&WS[wsr * 132 + wsc + 4] = *(const float4*)&W[(size_t)(kt * 16 + wsr) * 128 + wsc + 4];
        __syncthreads();
        int seg = kt >> 2;
        int kc0 = (kt & 3) * 16 + kg * 8;
        const float* Abase = &ASEG[seg * 1024];
#pragma unroll
        for (int kk = 0; kk < 8; kk++) {
            int kci = kc0 + kk;
            float a0 = Abase[(ty * 4 + 0) * 64 + kci];
            float a1 = Abase[(ty * 4 + 1) * 64 + kci];
            float a2 = Abase[(ty * 4 + 2) * 64 + kci];
            float a3 = Abase[(ty * 4 + 3) * 64 + kci];
            float4 wv = *(const float4*)&WS[(kg * 8 + kk) * 132 + tx * 4];
            float wvv[4] = { wv.x, wv.y, wv.z, wv.w };
#pragma unroll
            for (int cc = 0; cc < 4; cc++) {
                acc[0][cc] += a0 * wvv[cc];
                acc[1][cc] += a1 * wvv[cc];
                acc[2][cc] += a2 * wvv[cc];
                acc[3][cc] += a3 * wvv[cc];
            }
        }
        __syncthreads();
    }
#pragma unroll
    for (int rr = 0; rr < 4; rr++)
#pragma unroll
        for (int cc = 0; cc < 4; cc++)
            PRED[kg * 2048 + (ty * 4 + rr) * 128 + tx * 4 + cc] = acc[rr][cc];
    __syncthreads();
    for (int i = tid; i < 2048; i += 256) {
        int r = i >> 7, c = i & 127;
        float v = PRED[i] + PRED[2048 + i] + bias[c];
        float s = 1.f / (1.f + __expf(-v));
        size_t grow = (size_t)(b * Nn + n0 + r);
        if (c < 64) z[grow * 64 + c] = s;
        else hr[grow * 64 + (c - 64)] = ASEG[r * 64 + (c - 64)] * s;
    }
}

// LDS layout cell2: HS@0[32][68], L1s@2176[16][36], L2s@2752[16][36],
// WS2@3328[16][68]=1088, ASEG@4416[6][16][64]; PRED aliases lds[0..4095]
__global__ __launch_bounds__(256) void k_cell2(
        const float* __restrict__ hrp, const float* __restrict__ x,
        const float* __restrict__ t1x, const float* __restrict__ t2x,
        const float* __restrict__ L1, const float* __restrict__ L2,
        const float* __restrict__ W, const float* __restrict__ bias,
        const float* __restrict__ z, float* __restrict__ h, int t) {
    __shared__ float lds[10560];
    float* HS   = lds;
    float* L1s  = lds + 2176;
    float* L2s  = lds + 2752;
    float* WS   = lds + 3328;
    float* ASEG = lds + 4416;
    float* PRED = lds;

    int tid = threadIdx.x;
    int b = blockIdx.x >> 5;
    int n0 = (blockIdx.x & 31) * 16;
    const float* hb = hrp + (size_t)b * NC;
    size_t hoff = ((size_t)b * Nn + n0) * 64;
    size_t xoff = ((size_t)(b * Tn + t) * Nn + n0) * 64;

    {
        int r = tid >> 4, c4 = (tid & 15) * 4;
        *(float4*)&ASEG[0 * 1024 + r * 64 + c4] = *(const float4*)&hrp[hoff + (size_t)r * 64 + c4];
        *(float4*)&ASEG[3 * 1024 + r * 64 + c4] = *(const float4*)&x[xoff + (size_t)r * 64 + c4];
        *(float4*)&ASEG[4 * 1024 + r * 64 + c4] = *(const float4*)&t1x[xoff + (size_t)r * 64 + c4];
        *(float4*)&ASEG[5 * 1024 + r * 64 + c4] = *(const float4*)&t2x[xoff + (size_t)r * 64 + c4];
    }

    int rp = (tid >> 4) & 7, cg = tid & 15, kg = tid >> 7;
    int r0 = rp * 2, r1 = r0 + 1;
    float acc1[2][4] = {}, acc2[2][4] = {};
    int hsr = tid >> 4, hsc = (tid & 15) * 4;
    int llr = (tid & 127) >> 3, llc = (tid & 7) * 4;
    for (int kc = 0; kc < 512; kc += 32) {
        *(float4*)&HS[hsr * 68 + hsc] =
            *(const float4*)&hb[(size_t)(kc + hsr) * 64 + hsc];
        *(float4*)&HS[(hsr + 16) * 68 + hsc] =
            *(const float4*)&hb[(size_t)(kc + hsr + 16) * 64 + hsc];
        {
            const float* Lsrc = (tid < 128) ? L1 : L2;
            float* Ldst = (tid < 128) ? L1s : L2s;
            *(float4*)&Ldst[llr * 36 + llc] =
                *(const float4*)&Lsrc[(size_t)(n0 + llr) * 512 + kc + llc];
        }
        __syncthreads();
#pragma unroll
        for (int kk = 0; kk < 16; kk++) {
            int m = kg * 16 + kk;
            float l1a = L1s[r0 * 36 + m], l1b = L1s[r1 * 36 + m];
            float l2a = L2s[r0 * 36 + m], l2b = L2s[r1 * 36 + m];
            float4 hv = *(const float4*)&HS[m * 68 + cg * 4];
            float hvv[4] = { hv.x, hv.y, hv.z, hv.w };
#pragma unroll
            for (int j = 0; j < 4; j++) {
                acc1[0][j] += l1a * hvv[j];
                acc1[1][j] += l1b * hvv[j];
                acc2[0][j] += l2a * hvv[j];
                acc2[1][j] += l2b * hvv[j];
            }
        }
        __syncthreads();
    }
#pragma unroll
    for (int rr = 0; rr < 2; rr++)
#pragma unroll
        for (int j = 0; j < 4; j++) {
            PRED[((0 * 2 + kg) * 16 + r0 + rr) * 64 + cg * 4 + j] = acc1[rr][j];
            PRED[((1 * 2 + kg) * 16 + r0 + rr) * 64 + cg * 4 + j] = acc2[rr][j];
        }
    __syncthreads();
    for (int i = tid; i < 2048; i += 256) {
        int u = i >> 10, rc = i & 1023;
        ASEG[(1 + u) * 1024 + rc] = PRED[(u * 2 + 0) * 1024 + rc] + PRED[(u * 2 + 1) * 1024 + rc];
    }
    __syncthreads();

    // ---- phase B: ht[16][64] = A[16][384] @ W[384][64], k-split-2 ----
    int ty = (tid >> 4) & 7, tx = tid & 15;
    float acc[2][4] = {};
    int wsr = tid >> 4, wsc = (tid & 15) * 4;
    for (int kt = 0; kt < 24; kt++) {
        *(float4*)&WS[wsr * 68 + wsc] = *(const float4*)&W[(size_t)(kt * 16 + wsr) * 64 + wsc];
        __syncthreads();
        int seg = kt >> 2;
        int kc0 = (kt & 3) * 16 + kg * 8;
        const float* Abase = &ASEG[seg * 1024];
#pragma unroll
        for (int kk = 0; kk < 8; kk++) {
            int kci = kc0 + kk;
            float a0 = Abase[(ty * 2 + 0) * 64 + kci];
            float a1 = Abase[(ty * 2 + 1) * 64 + kci];
            float4 wv = *(const float4*)&WS[(kg * 8 + kk) * 68 + tx * 4];
            float wvv[4] = { wv.x, wv.y, wv.z, wv.w };
#pragma unroll
            for (int cc = 0; cc < 4; cc++) {
                acc[0][cc] += a0 * wvv[cc];
                acc[1][cc] += a1 * wvv[cc];
            }
        }
        __syncthreads();
    }
#pragma unroll
    for (int rr = 0; rr < 2; rr++)
#pragma unroll
        for (int cc = 0; cc < 4; cc++)
            PRED[kg * 1024 + (ty * 2 + rr) * 64 + tx * 4 + cc] = acc[rr][cc];
    __syncthreads();
    for (int i = tid; i < 1024; i += 256) {
        int r = i >> 6, c = i & 63;
        float v = PRED[i] + PRED[1024 + i] + bias[c];
        float htv = tanhf(v);
        size_t p = ((size_t)(b * Nn + n0 + r)) * 64 + c;
        float zz = z[p], hold = h[p];
        h[p] = zz * hold + (1.f - zz) * htv;
    }
}

// ---------------- projections ----------------
__global__ __launch_bounds__(256) void k_proj(
        const float* __restrict__ h, const float* __restrict__ W1cat,
        const float* __restrict__ b1,
        float* __restrict__ sproj, float* __restrict__ tproj) {
    __shared__ float As[16][33];
    __shared__ float Ws[16 * 128];
    int tid = threadIdx.x;
    int row0 = blockIdx.x * 32;
    const float* hp = h + (size_t)row0 * 64;
    float acc[2][8] = {};
    int tx = tid & 15, ty = tid >> 4;
    int lr = tid >> 3;
    int lk = (tid & 7) * 2;
    int wk = tid >> 4;
    int wc = (tid & 15) * 8;
    for (int kt = 0; kt < 4; kt++) {
        int c0 = kt * 16;
        float2 a2 = *(const float2*)&hp[lr * 64 + c0 + lk];
        const float4* wsrc = (const float4*)&W1cat[(size_t)(kt * 16 + wk) * 128 + wc];
        float4 w0 = wsrc[0], w1 = wsrc[1];
        As[lk][lr] = a2.x;
        As[lk + 1][lr] = a2.y;
        *(float4*)&Ws[wk * 128 + wc] = w0;
        *(float4*)&Ws[wk * 128 + wc + 4] = w1;
        __syncthreads();
#pragma unroll
        for (int kk = 0; kk < 16; kk++) {
            float a0 = As[kk][ty * 2 + 0];
            float a1 = As[kk][ty * 2 + 1];
            float4 p0 = *(const float4*)&Ws[kk * 128 + tx * 8];
            float4 p1 = *(const float4*)&Ws[kk * 128 + tx * 8 + 4];
            float w[8] = { p0.x, p0.y, p0.z, p0.w, p1.x, p1.y, p1.z, p1.w };
#pragma unroll
            for (int cc = 0; cc < 8; cc++) {
                acc[0][cc] += a0 * w[cc];
                acc[1][cc] += a1 * w[cc];
            }
        }
        __syncthreads();
    }
#pragma unroll
    for (int rr = 0; rr < 2; rr++) {
        int row = row0 + ty * 2 + rr;
#pragma unroll
        for (int cc = 0; cc < 8; cc++) {
            int col = tx * 8 + cc;
            float v = acc[rr][cc];
            if (col < 64) sproj[(size_t)row * 64 + col] = v + b1[col];
            else tproj[(size_t)row * 64 + (col - 64)] = v;
        }
    }
}

// ---------------- logits ----------------
__global__ __launch_bounds__(256) void k_logits(
        const float* __restrict__ sproj, const float* __restrict__ tproj,
        const float* __restrict__ W2, const float* __restrict__ b2,
        float* __restrict__ out) {
    __shared__ float sp[32 * 64];
    __shared__ float tp[64 * 65];
    __shared__ float w2s[64];
    int tid = threadIdx.x;
    int bb = blockIdx.x >> 7;
    int st = (blockIdx.x >> 3) & 15;
    int tt = blockIdx.x & 7;
    const float* spg = sproj + ((size_t)bb * Nn + st * 32) * 64;
    const float* tpg = tproj + ((size_t)bb * Nn + tt * 64) * 64;
    for (int i = tid; i < 2048; i += 256) sp[i] = spg[i];
    for (int i = tid; i < 4096; i += 256) {
        int tl = i >> 6, hh = i & 63;
        tp[tl * 65 + hh] = tpg[i];
    }
    if (tid < 64) w2s[tid] = W2[tid];
    __syncthreads();
    float bias = *b2;
    int tl = tid & 63, sg = tid >> 6;
    for (int si = 0; si < 8; si++) {
        int s = sg * 8 + si;
        float acc = bias;
#pragma unroll 8
        for (int hh = 0; hh < 64; hh++) {
            float v = sp[s * 64 + hh] + tp[tl * 65 + hh];
            acc += fmaxf(v, 0.f) * w2s[hh];
        }
        out[(size_t)bb * Nn * Nn + (size_t)(st * 32 + s) * Nn + tt * 64 + tl] = acc;
    }
}

// ---------------- host ----------------
extern "C" void kernel_launch(void* const* d_in, const int* in_sizes, int n_in,
                              void* d_out, int out_size, void* d_ws, size_t ws_size,
                              hipStream_t stream) {
    const float* x  = (const float*)d_in[0];
    const float* ew = (const float*)d_in[1];
    const float* Wx = (const float*)d_in[2];
    const float* bx = (const float*)d_in[3];
    const float* Wh = (const float*)d_in[4];
    const float* bh = (const float*)d_in[5];
    const float* W1 = (const float*)d_in[6];
    const float* b1 = (const float*)d_in[7];
    const float* W2 = (const float*)d_in[8];
    const float* b2 = (const float*)d_in[9];
    const int* ei   = (const int*)d_in[10];
    const int* esrc = ei;
    const int* edst = ei + En;

    float* ws = (float*)d_ws;
    float* deg   = ws + OFF_DEG;
    float* dinv  = ws + OFF_DINV;
    float* L1d   = ws + OFF_L1D;
    float* L2d   = ws + OFF_L2D;
    float* WzrC  = ws + OFF_WZR;
    float* WhC   = ws + OFF_WHT;
    float* bzr   = ws + OFF_BZR;
    float* bht   = ws + OFF_BHT;
    float* W1cat = ws + OFF_W1C;
    float* T1x   = ws + OFF_T1X;
    float* T2x   = ws + OFF_T2X;
    float* h     = ws + OFF_H;
    float* z     = ws + OFF_Z;
    float* hr    = ws + OFF_HR;
    float* sproj = ws + OFF_SP;
    float* tproj = ws + OFF_TP;
    float* out   = (float*)d_out;

    hipMemsetAsync(deg, 0, 512 * sizeof(float), stream);
    hipMemsetAsync(L1d, 0, (size_t)Nn * Nn * sizeof(float), stream);
    hipMemsetAsync(h, 0, (size_t)Bn * NC * sizeof(float), stream);

    k_deg<<<64, 256, 0, stream>>>(ew, esrc, deg);
    k_dinv<<<2, 256, 0, stream>>>(deg, dinv);
    k_nwdense<<<64, 256, 0, stream>>>(ew, esrc, edst, dinv, L1d);
    k_l2<<<64, 256, 0, stream>>>(L1d, L2d);
    k_repack<<<(156032 + 255) / 256, 256, 0, stream>>>(Wx, bx, Wh, bh, W1,
                                                       WzrC, WhC, bzr, bht, W1cat);

    k_lmm<<<Bn * Tn * 8, 256, 0, stream>>>(L1d, x, T1x);
    k_lmm<<<Bn * Tn * 8, 256, 0, stream>>>(L2d, x, T2x);

    for (int t = 0; t < Tn; t++) {
        for (int l = 0; l < Ln; l++) {
            k_cell1<<<256, 256, 0, stream>>>(h, x, T1x, T2x, L1d, L2d,
                                             WzrC + (size_t)l * 384 * 128,
                                             bzr + l * 128, z, hr, t);
            k_cell2<<<256, 256, 0, stream>>>(hr, x, T1x, T2x, L1d, L2d,
                                             WhC + (size_t)l * 384 * 64,
                                             bht + l * 64, z, h, t);
        }
    }

    k_proj<<<128, 256, 0, stream>>>(h, W1cat, b1, sproj, tproj);
    k_logits<<<Bn * 16 * 8, 256, 0, stream>>>(sproj, tproj, W2, b2, out);
}